// Round 7
// baseline (45.920 us; speedup 1.0000x reference)
//
#include <hip/hip_runtime.h>
#include <math.h>

#define D_MODEL 1024
#define KSEL    256
#define TPB     256          // threads per block == float4 per row
#define RPB     16           // rows per block
#define QW      (D_MODEL/4)  // 256 float4 per row

typedef float v4f __attribute__((ext_vector_type(4)));

__device__ __forceinline__ float softplus_f(float z) {
    return (z > 20.0f) ? z : log1pf(__expf(z));
}

// tanh-approx GELU with fast exp/rcp; max |err| vs exact erf-GELU ~3e-4
__device__ __forceinline__ float gelu_fast(float x) {
    const float u = 0.7978845608028654f * x * (1.0f + 0.044715f * x * x);
    const float e = __expf(2.0f * u);
    const float t = 1.0f - 2.0f * __builtin_amdgcn_rcpf(e + 1.0f);
    return 0.5f * x * (1.0f + t);
}

__device__ __forceinline__ v4f gelu4(const v4f v, const float g) {
    v4f o;
    o.x = gelu_fast(v.x) * g;
    o.y = gelu_fast(v.y) * g;
    o.z = gelu_fast(v.z) * g;
    o.w = gelu_fast(v.w) * g;
    return o;
}

__global__ __launch_bounds__(TPB, 8) void gelu_gate_kernel(
    const float* __restrict__ x,
    const float* __restrict__ log_sigma_raw,
    const float* __restrict__ log_w_raw,
    const float* __restrict__ ema_prob,
    float* __restrict__ out,
    int nrows)
{
    const int t    = threadIdx.x;
    const int row0 = blockIdx.x * RPB;
    if (row0 >= nrows) return;

    __shared__ int s_ok4[4];

    // ---- once-per-block prologue (all in registers; one barrier) ----
    const float4 ep = reinterpret_cast<const float4*>(ema_prob)[t];   // 4 KB, L1/L2-resident
    const unsigned int ref = __float_as_uint(ema_prob[0]);            // uniform addr -> s_load
    const bool okt = (__float_as_uint(ep.x) == ref) &
                     (__float_as_uint(ep.y) == ref) &
                     (__float_as_uint(ep.z) == ref) &
                     (__float_as_uint(ep.w) == ref);
    const int wall = __all(okt);
    if ((t & 63) == 0) s_ok4[t >> 6] = wall;
    __syncthreads();
    const bool uniform = (s_ok4[0] & s_ok4[1] & s_ok4[2] & s_ok4[3]) != 0;

    // redundant per-thread scalar math (no serialization, no broadcast barrier)
    const float sigma = softplus_f(log_sigma_raw[0]) + 0.01f;
    const float w     = softplus_f(log_w_raw[0]);

    if (uniform) {
        // ---- fast path: software-pipelined streaming, 4-deep chunks, 1-ahead prefetch ----
        const float g = 1.0f + w * tanhf(sigma * (1.0f - __uint_as_float(ref)));
        const size_t base = (size_t)row0 * QW + t;
        const v4f* xp = reinterpret_cast<const v4f*>(x) + base;
        v4f*       op = reinterpret_cast<v4f*>(out)     + base;

        if (row0 + RPB <= nrows) {
            v4f A0 = xp[0 * QW];
            v4f A1 = xp[1 * QW];
            v4f A2 = xp[2 * QW];
            v4f A3 = xp[3 * QW];

            #pragma unroll
            for (int j = 0; j < 4; ++j) {
                v4f B0, B1, B2, B3;
                if (j < 3) {
                    B0 = xp[(size_t)(4 * j + 4) * QW];
                    B1 = xp[(size_t)(4 * j + 5) * QW];
                    B2 = xp[(size_t)(4 * j + 6) * QW];
                    B3 = xp[(size_t)(4 * j + 7) * QW];
                }
                __builtin_nontemporal_store(gelu4(A0, g), &op[(size_t)(4 * j + 0) * QW]);
                __builtin_nontemporal_store(gelu4(A1, g), &op[(size_t)(4 * j + 1) * QW]);
                __builtin_nontemporal_store(gelu4(A2, g), &op[(size_t)(4 * j + 2) * QW]);
                __builtin_nontemporal_store(gelu4(A3, g), &op[(size_t)(4 * j + 3) * QW]);
                if (j < 3) { A0 = B0; A1 = B1; A2 = B2; A3 = B3; }
            }
        } else {
            const int rend = nrows - row0;
            for (int r = 0; r < rend; ++r) {
                const v4f v = xp[(size_t)r * QW];
                __builtin_nontemporal_store(gelu4(v, g), &op[(size_t)r * QW]);
            }
        }
        return;
    }

    // ---- general path: per-row radix-8 top-k select over |x| (correctness fallback) ----
    const float rr[4] = {1.0f - ep.x, 1.0f - ep.y, 1.0f - ep.z, 1.0f - ep.w};

    __shared__ unsigned int hist[256];
    __shared__ unsigned int s_sel, s_cntgt;
    __shared__ float s_sgt[4], s_seq[4];
    __shared__ unsigned int s_neq[4];
    __shared__ float s_gate;

    const int rend = (row0 + RPB <= nrows) ? RPB : (nrows - row0);
    for (int r = 0; r < rend; ++r) {
        const size_t rowbase = (size_t)(row0 + r) * QW + t;
        const float4 v = reinterpret_cast<const float4*>(x)[rowbase];

        const unsigned int a0 = __float_as_uint(v.x) & 0x7fffffffu;
        const unsigned int a1 = __float_as_uint(v.y) & 0x7fffffffu;
        const unsigned int a2 = __float_as_uint(v.z) & 0x7fffffffu;
        const unsigned int a3 = __float_as_uint(v.w) & 0x7fffffffu;

        unsigned int prefix = 0;
        unsigned int kk = KSEL;

        #pragma unroll
        for (int p = 3; p >= 0; --p) {
            const int shift = p * 8;
            hist[t] = 0u;
            __syncthreads();

            const unsigned int hm = (p == 3) ? 0u : (0xffffffffu << (shift + 8));
            if (((a0 ^ prefix) & hm) == 0u) atomicAdd(&hist[(a0 >> shift) & 255u], 1u);
            if (((a1 ^ prefix) & hm) == 0u) atomicAdd(&hist[(a1 >> shift) & 255u], 1u);
            if (((a2 ^ prefix) & hm) == 0u) atomicAdd(&hist[(a2 >> shift) & 255u], 1u);
            if (((a3 ^ prefix) & hm) == 0u) atomicAdd(&hist[(a3 >> shift) & 255u], 1u);
            __syncthreads();

            #pragma unroll
            for (int off = 1; off < 256; off <<= 1) {
                unsigned int val = hist[t] + ((t + off < 256) ? hist[t + off] : 0u);
                __syncthreads();
                hist[t] = val;
                __syncthreads();
            }

            const unsigned int ge      = hist[t];
            const unsigned int ge_next = (t < 255) ? hist[t + 1] : 0u;
            if (ge >= kk && ge_next < kk) { s_sel = (unsigned int)t; s_cntgt = ge_next; }
            __syncthreads();

            prefix |= (s_sel << shift);
            kk     -= s_cntgt;
        }

        float sgt = 0.0f, seq = 0.0f;
        unsigned int neq = 0u;
        {
            const unsigned int aa[4] = {a0, a1, a2, a3};
            #pragma unroll
            for (int e = 0; e < 4; ++e) {
                if (aa[e] > prefix) {
                    sgt += rr[e];
                } else if (aa[e] == prefix) {
                    seq += rr[e];
                    neq += 1u;
                }
            }
        }

        #pragma unroll
        for (int off = 32; off >= 1; off >>= 1) {
            sgt += __shfl_down(sgt, off);
            seq += __shfl_down(seq, off);
            neq += __shfl_down(neq, off);
        }
        const int wave = t >> 6;
        if ((t & 63) == 0) { s_sgt[wave] = sgt; s_seq[wave] = seq; s_neq[wave] = neq; }
        __syncthreads();

        if (t == 0) {
            float tot_gt = 0.0f, tot_eq = 0.0f;
            unsigned int tot_ne = 0u;
            #pragma unroll
            for (int wv = 0; wv < 4; ++wv) { tot_gt += s_sgt[wv]; tot_eq += s_seq[wv]; tot_ne += s_neq[wv]; }
            const float raw = (tot_gt + tot_eq * ((float)kk / (float)tot_ne)) * (1.0f / (float)KSEL);
            s_gate = 1.0f + w * tanhf(sigma * raw);
        }
        __syncthreads();

        const float gate = s_gate;
        float4 o;
        o.x = gelu_fast(v.x) * gate;
        o.y = gelu_fast(v.y) * gate;
        o.z = gelu_fast(v.z) * gate;
        o.w = gelu_fast(v.w) * gate;
        reinterpret_cast<float4*>(out)[rowbase] = o;
        __syncthreads();  // protect LDS reuse before next row
    }
}

extern "C" void kernel_launch(void* const* d_in, const int* in_sizes, int n_in,
                              void* d_out, int out_size, void* d_ws, size_t ws_size,
                              hipStream_t stream) {
    const float* x             = (const float*)d_in[0];
    const float* log_sigma_raw = (const float*)d_in[1];
    const float* log_w_raw     = (const float*)d_in[2];
    const float* ema_prob      = (const float*)d_in[3];
    float* out = (float*)d_out;
    (void)d_ws; (void)ws_size;

    const int nrows = in_sizes[0] / D_MODEL;          // 4*8192 = 32768
    const int nblocks = (nrows + RPB - 1) / RPB;      // 2048 -> exactly 8 blocks/CU
    gelu_gate_kernel<<<nblocks, TPB, 0, stream>>>(x, log_sigma_raw, log_w_raw, ema_prob, out, nrows);
}

// Round 8
// 45.776 us; speedup vs baseline: 1.0032x; 1.0032x over previous
//
#include <hip/hip_runtime.h>
#include <math.h>

#define D_MODEL 1024
#define KSEL    256
#define TPB     256          // threads per block == float4 per row
#define RPB     16           // rows per block
#define QW      (D_MODEL/4)  // 256 float4 per row

typedef float v4f __attribute__((ext_vector_type(4)));

__device__ __forceinline__ float softplus_f(float z) {
    return (z > 20.0f) ? z : log1pf(__expf(z));
}

// tanh-approx GELU with fast exp/rcp; max |err| vs exact erf-GELU ~3e-4
__device__ __forceinline__ float gelu_fast(float x) {
    const float u = 0.7978845608028654f * x * (1.0f + 0.044715f * x * x);
    const float e = __expf(2.0f * u);
    const float t = 1.0f - 2.0f * __builtin_amdgcn_rcpf(e + 1.0f);
    return 0.5f * x * (1.0f + t);
}

__device__ __forceinline__ v4f gelu4(const v4f v, const float g) {
    v4f o;
    o.x = gelu_fast(v.x) * g;
    o.y = gelu_fast(v.y) * g;
    o.z = gelu_fast(v.z) * g;
    o.w = gelu_fast(v.w) * g;
    return o;
}

__global__ __launch_bounds__(TPB, 8) void gelu_gate_kernel(
    const float* __restrict__ x,
    const float* __restrict__ log_sigma_raw,
    const float* __restrict__ log_w_raw,
    const float* __restrict__ ema_prob,
    float* __restrict__ out,
    int nrows)
{
    const int t    = threadIdx.x;
    const int row0 = blockIdx.x * RPB;
    if (row0 >= nrows) return;

    __shared__ int s_ok4[4];

    // ---- once-per-block prologue (registers only; one barrier) ----
    const float4 ep = reinterpret_cast<const float4*>(ema_prob)[t];   // 4 KB, L1/L2-resident
    const unsigned int ref = __float_as_uint(ema_prob[0]);            // uniform addr -> s_load
    const bool okt = (__float_as_uint(ep.x) == ref) &
                     (__float_as_uint(ep.y) == ref) &
                     (__float_as_uint(ep.z) == ref) &
                     (__float_as_uint(ep.w) == ref);
    const int wall = __all(okt);
    if ((t & 63) == 0) s_ok4[t >> 6] = wall;
    __syncthreads();
    const bool uniform = (s_ok4[0] & s_ok4[1] & s_ok4[2] & s_ok4[3]) != 0;

    // redundant per-thread scalar math (once per block, amortized over 16 rows)
    const float sigma = softplus_f(log_sigma_raw[0]) + 0.01f;
    const float w     = softplus_f(log_w_raw[0]);

    if (uniform) {
        // ---- fast path: software-pipelined streaming, 4-deep chunks, 1-ahead prefetch,
        //      PLAIN stores (L2/L3 write-combining; nt stores measured -3..-5%) ----
        const float g = 1.0f + w * tanhf(sigma * (1.0f - __uint_as_float(ref)));
        const size_t base = (size_t)row0 * QW + t;
        const v4f* xp = reinterpret_cast<const v4f*>(x) + base;
        v4f*       op = reinterpret_cast<v4f*>(out)     + base;

        if (row0 + RPB <= nrows) {
            v4f A0 = xp[0 * QW];
            v4f A1 = xp[1 * QW];
            v4f A2 = xp[2 * QW];
            v4f A3 = xp[3 * QW];

            #pragma unroll
            for (int j = 0; j < 4; ++j) {
                v4f B0, B1, B2, B3;
                if (j < 3) {
                    B0 = xp[(size_t)(4 * j + 4) * QW];
                    B1 = xp[(size_t)(4 * j + 5) * QW];
                    B2 = xp[(size_t)(4 * j + 6) * QW];
                    B3 = xp[(size_t)(4 * j + 7) * QW];
                }
                op[(size_t)(4 * j + 0) * QW] = gelu4(A0, g);
                op[(size_t)(4 * j + 1) * QW] = gelu4(A1, g);
                op[(size_t)(4 * j + 2) * QW] = gelu4(A2, g);
                op[(size_t)(4 * j + 3) * QW] = gelu4(A3, g);
                if (j < 3) { A0 = B0; A1 = B1; A2 = B2; A3 = B3; }
            }
        } else {
            const int rend = nrows - row0;
            for (int r = 0; r < rend; ++r) {
                const v4f v = xp[(size_t)r * QW];
                op[(size_t)r * QW] = gelu4(v, g);
            }
        }
        return;
    }

    // ---- general path: per-row radix-8 top-k select over |x| (correctness fallback) ----
    const float rr[4] = {1.0f - ep.x, 1.0f - ep.y, 1.0f - ep.z, 1.0f - ep.w};

    __shared__ unsigned int hist[256];
    __shared__ unsigned int s_sel, s_cntgt;
    __shared__ float s_sgt[4], s_seq[4];
    __shared__ unsigned int s_neq[4];
    __shared__ float s_gate;

    const int rend = (row0 + RPB <= nrows) ? RPB : (nrows - row0);
    for (int r = 0; r < rend; ++r) {
        const size_t rowbase = (size_t)(row0 + r) * QW + t;
        const float4 v = reinterpret_cast<const float4*>(x)[rowbase];

        const unsigned int a0 = __float_as_uint(v.x) & 0x7fffffffu;
        const unsigned int a1 = __float_as_uint(v.y) & 0x7fffffffu;
        const unsigned int a2 = __float_as_uint(v.z) & 0x7fffffffu;
        const unsigned int a3 = __float_as_uint(v.w) & 0x7fffffffu;

        unsigned int prefix = 0;
        unsigned int kk = KSEL;

        #pragma unroll
        for (int p = 3; p >= 0; --p) {
            const int shift = p * 8;
            hist[t] = 0u;
            __syncthreads();

            const unsigned int hm = (p == 3) ? 0u : (0xffffffffu << (shift + 8));
            if (((a0 ^ prefix) & hm) == 0u) atomicAdd(&hist[(a0 >> shift) & 255u], 1u);
            if (((a1 ^ prefix) & hm) == 0u) atomicAdd(&hist[(a1 >> shift) & 255u], 1u);
            if (((a2 ^ prefix) & hm) == 0u) atomicAdd(&hist[(a2 >> shift) & 255u], 1u);
            if (((a3 ^ prefix) & hm) == 0u) atomicAdd(&hist[(a3 >> shift) & 255u], 1u);
            __syncthreads();

            #pragma unroll
            for (int off = 1; off < 256; off <<= 1) {
                unsigned int val = hist[t] + ((t + off < 256) ? hist[t + off] : 0u);
                __syncthreads();
                hist[t] = val;
                __syncthreads();
            }

            const unsigned int ge      = hist[t];
            const unsigned int ge_next = (t < 255) ? hist[t + 1] : 0u;
            if (ge >= kk && ge_next < kk) { s_sel = (unsigned int)t; s_cntgt = ge_next; }
            __syncthreads();

            prefix |= (s_sel << shift);
            kk     -= s_cntgt;
        }

        float sgt = 0.0f, seq = 0.0f;
        unsigned int neq = 0u;
        {
            const unsigned int aa[4] = {a0, a1, a2, a3};
            #pragma unroll
            for (int e = 0; e < 4; ++e) {
                if (aa[e] > prefix) {
                    sgt += rr[e];
                } else if (aa[e] == prefix) {
                    seq += rr[e];
                    neq += 1u;
                }
            }
        }

        #pragma unroll
        for (int off = 32; off >= 1; off >>= 1) {
            sgt += __shfl_down(sgt, off);
            seq += __shfl_down(seq, off);
            neq += __shfl_down(neq, off);
        }
        const int wave = t >> 6;
        if ((t & 63) == 0) { s_sgt[wave] = sgt; s_seq[wave] = seq; s_neq[wave] = neq; }
        __syncthreads();

        if (t == 0) {
            float tot_gt = 0.0f, tot_eq = 0.0f;
            unsigned int tot_ne = 0u;
            #pragma unroll
            for (int wv = 0; wv < 4; ++wv) { tot_gt += s_sgt[wv]; tot_eq += s_seq[wv]; tot_ne += s_neq[wv]; }
            const float raw = (tot_gt + tot_eq * ((float)kk / (float)tot_ne)) * (1.0f / (float)KSEL);
            s_gate = 1.0f + w * tanhf(sigma * raw);
        }
        __syncthreads();

        const float gate = s_gate;
        float4 o;
        o.x = gelu_fast(v.x) * gate;
        o.y = gelu_fast(v.y) * gate;
        o.z = gelu_fast(v.z) * gate;
        o.w = gelu_fast(v.w) * gate;
        reinterpret_cast<float4*>(out)[rowbase] = o;
        __syncthreads();  // protect LDS reuse before next row
    }
}

extern "C" void kernel_launch(void* const* d_in, const int* in_sizes, int n_in,
                              void* d_out, int out_size, void* d_ws, size_t ws_size,
                              hipStream_t stream) {
    const float* x             = (const float*)d_in[0];
    const float* log_sigma_raw = (const float*)d_in[1];
    const float* log_w_raw     = (const float*)d_in[2];
    const float* ema_prob      = (const float*)d_in[3];
    float* out = (float*)d_out;
    (void)d_ws; (void)ws_size;

    const int nrows = in_sizes[0] / D_MODEL;          // 4*8192 = 32768
    const int nblocks = (nrows + RPB - 1) / RPB;      // 2048 -> 8 blocks/CU
    gelu_gate_kernel<<<nblocks, TPB, 0, stream>>>(x, log_sigma_raw, log_w_raw, ema_prob, out, nrows);
}

// Round 10
// 45.116 us; speedup vs baseline: 1.0178x; 1.0146x over previous
//
#include <hip/hip_runtime.h>
#include <math.h>

#define D_MODEL 1024
#define KSEL    256
#define TPB     256          // one float4 lane-slice per row
#define RPB     4            // rows per block (loads explicitly hoisted for MLP)
#define QW      (D_MODEL/4)  // 256 float4 per row

typedef float v4f __attribute__((ext_vector_type(4)));   // native vector for nt-store

__device__ __forceinline__ float softplus_f(float z) {
    return (z > 20.0f) ? z : log1pf(__expf(z));
}

// tanh-approx GELU with fast exp/rcp; max |err| vs exact erf-GELU ~3e-4
__device__ __forceinline__ float gelu_fast(float x) {
    const float u = 0.7978845608028654f * x * (1.0f + 0.044715f * x * x);
    const float e = __expf(2.0f * u);
    const float t = 1.0f - 2.0f * __builtin_amdgcn_rcpf(e + 1.0f);
    return 0.5f * x * (1.0f + t);
}

__global__ __launch_bounds__(TPB, 8) void gelu_gate_kernel(
    const float* __restrict__ x,
    const float* __restrict__ log_sigma_raw,
    const float* __restrict__ log_w_raw,
    const float* __restrict__ ema_prob,
    float* __restrict__ out,
    int nrows)
{
    const int t    = threadIdx.x;
    const int row0 = blockIdx.x * RPB;
    if (row0 >= nrows) return;

    __shared__ int   s_ok4[4];
    __shared__ float s_par[3];   // sigma, w, uniform gate

    // ---- once-per-block prologue ----
    const float4 ep = reinterpret_cast<const float4*>(ema_prob)[t];   // 4 KB, L1/L2-resident
    const unsigned int ref = __float_as_uint(ema_prob[0]);            // uniform addr -> s_load
    const bool okt = (__float_as_uint(ep.x) == ref) &
                     (__float_as_uint(ep.y) == ref) &
                     (__float_as_uint(ep.z) == ref) &
                     (__float_as_uint(ep.w) == ref);
    const int wall = __all(okt);
    if ((t & 63) == 0) s_ok4[t >> 6] = wall;
    if (t == 0) {
        const float sigma = softplus_f(log_sigma_raw[0]) + 0.01f;
        const float w     = softplus_f(log_w_raw[0]);
        s_par[0] = sigma;
        s_par[1] = w;
        s_par[2] = 1.0f + w * tanhf(sigma * (1.0f - __uint_as_float(ref)));
    }
    __syncthreads();
    const bool uniform = (s_ok4[0] & s_ok4[1] & s_ok4[2] & s_ok4[3]) != 0;

    if (uniform) {
        // ---- fast path: pure streaming; 4 loads hoisted -> 4 outstanding per wave ----
        const float g = s_par[2];
        const size_t base = (size_t)row0 * QW + t;
        const v4f* xp = reinterpret_cast<const v4f*>(x) + base;
        v4f*       op = reinterpret_cast<v4f*>(out)     + base;

        if (row0 + RPB <= nrows) {
            const v4f v0 = xp[0 * QW];
            const v4f v1 = xp[1 * QW];
            const v4f v2 = xp[2 * QW];
            const v4f v3 = xp[3 * QW];

            v4f o;
            o.x = gelu_fast(v0.x) * g; o.y = gelu_fast(v0.y) * g;
            o.z = gelu_fast(v0.z) * g; o.w = gelu_fast(v0.w) * g;
            __builtin_nontemporal_store(o, &op[0 * QW]);
            o.x = gelu_fast(v1.x) * g; o.y = gelu_fast(v1.y) * g;
            o.z = gelu_fast(v1.z) * g; o.w = gelu_fast(v1.w) * g;
            __builtin_nontemporal_store(o, &op[1 * QW]);
            o.x = gelu_fast(v2.x) * g; o.y = gelu_fast(v2.y) * g;
            o.z = gelu_fast(v2.z) * g; o.w = gelu_fast(v2.w) * g;
            __builtin_nontemporal_store(o, &op[2 * QW]);
            o.x = gelu_fast(v3.x) * g; o.y = gelu_fast(v3.y) * g;
            o.z = gelu_fast(v3.z) * g; o.w = gelu_fast(v3.w) * g;
            __builtin_nontemporal_store(o, &op[3 * QW]);
        } else {
            const int rend = nrows - row0;
            for (int r = 0; r < rend; ++r) {
                const v4f v = xp[(size_t)r * QW];
                v4f o;
                o.x = gelu_fast(v.x) * g;
                o.y = gelu_fast(v.y) * g;
                o.z = gelu_fast(v.z) * g;
                o.w = gelu_fast(v.w) * g;
                __builtin_nontemporal_store(o, &op[(size_t)r * QW]);
            }
        }
        return;
    }

    // ---- general path: per-row radix-8 top-k select over |x| ----
    const float sigma = s_par[0];
    const float w     = s_par[1];
    const float rr[4] = {1.0f - ep.x, 1.0f - ep.y, 1.0f - ep.z, 1.0f - ep.w};

    __shared__ unsigned int hist[256];
    __shared__ unsigned int s_sel, s_cntgt;
    __shared__ float s_sgt[4], s_seq[4];
    __shared__ unsigned int s_neq[4];
    __shared__ float s_gate;

    const int rend = (row0 + RPB <= nrows) ? RPB : (nrows - row0);
    for (int r = 0; r < rend; ++r) {
        const size_t rowbase = (size_t)(row0 + r) * QW + t;
        const float4 v = reinterpret_cast<const float4*>(x)[rowbase];

        const unsigned int a0 = __float_as_uint(v.x) & 0x7fffffffu;
        const unsigned int a1 = __float_as_uint(v.y) & 0x7fffffffu;
        const unsigned int a2 = __float_as_uint(v.z) & 0x7fffffffu;
        const unsigned int a3 = __float_as_uint(v.w) & 0x7fffffffu;

        unsigned int prefix = 0;
        unsigned int kk = KSEL;

        #pragma unroll
        for (int p = 3; p >= 0; --p) {
            const int shift = p * 8;
            hist[t] = 0u;
            __syncthreads();

            const unsigned int hm = (p == 3) ? 0u : (0xffffffffu << (shift + 8));
            if (((a0 ^ prefix) & hm) == 0u) atomicAdd(&hist[(a0 >> shift) & 255u], 1u);
            if (((a1 ^ prefix) & hm) == 0u) atomicAdd(&hist[(a1 >> shift) & 255u], 1u);
            if (((a2 ^ prefix) & hm) == 0u) atomicAdd(&hist[(a2 >> shift) & 255u], 1u);
            if (((a3 ^ prefix) & hm) == 0u) atomicAdd(&hist[(a3 >> shift) & 255u], 1u);
            __syncthreads();

            #pragma unroll
            for (int off = 1; off < 256; off <<= 1) {
                unsigned int val = hist[t] + ((t + off < 256) ? hist[t + off] : 0u);
                __syncthreads();
                hist[t] = val;
                __syncthreads();
            }

            const unsigned int ge      = hist[t];
            const unsigned int ge_next = (t < 255) ? hist[t + 1] : 0u;
            if (ge >= kk && ge_next < kk) { s_sel = (unsigned int)t; s_cntgt = ge_next; }
            __syncthreads();

            prefix |= (s_sel << shift);
            kk     -= s_cntgt;
        }

        float sgt = 0.0f, seq = 0.0f;
        unsigned int neq = 0u;
        {
            const unsigned int aa[4] = {a0, a1, a2, a3};
            #pragma unroll
            for (int e = 0; e < 4; ++e) {
                if (aa[e] > prefix) {
                    sgt += rr[e];
                } else if (aa[e] == prefix) {
                    seq += rr[e];
                    neq += 1u;
                }
            }
        }

        #pragma unroll
        for (int off = 32; off >= 1; off >>= 1) {
            sgt += __shfl_down(sgt, off);
            seq += __shfl_down(seq, off);
            neq += __shfl_down(neq, off);
        }
        const int wave = t >> 6;
        if ((t & 63) == 0) { s_sgt[wave] = sgt; s_seq[wave] = seq; s_neq[wave] = neq; }
        __syncthreads();

        if (t == 0) {
            float tot_gt = 0.0f, tot_eq = 0.0f;
            unsigned int tot_ne = 0u;
            #pragma unroll
            for (int wv = 0; wv < 4; ++wv) { tot_gt += s_sgt[wv]; tot_eq += s_seq[wv]; tot_ne += s_neq[wv]; }
            const float raw = (tot_gt + tot_eq * ((float)kk / (float)tot_ne)) * (1.0f / (float)KSEL);
            s_gate = 1.0f + w * tanhf(sigma * raw);
        }
        __syncthreads();

        const float gate = s_gate;
        float4 o;
        o.x = gelu_fast(v.x) * gate;
        o.y = gelu_fast(v.y) * gate;
        o.z = gelu_fast(v.z) * gate;
        o.w = gelu_fast(v.w) * gate;
        reinterpret_cast<float4*>(out)[rowbase] = o;
        __syncthreads();  // protect LDS reuse before next row
    }
}

extern "C" void kernel_launch(void* const* d_in, const int* in_sizes, int n_in,
                              void* d_out, int out_size, void* d_ws, size_t ws_size,
                              hipStream_t stream) {
    const float* x             = (const float*)d_in[0];
    const float* log_sigma_raw = (const float*)d_in[1];
    const float* log_w_raw     = (const float*)d_in[2];
    const float* ema_prob      = (const float*)d_in[3];
    float* out = (float*)d_out;
    (void)d_ws; (void)ws_size;

    const int nrows = in_sizes[0] / D_MODEL;          // 4*8192 = 32768
    const int nblocks = (nrows + RPB - 1) / RPB;      // 8192
    gelu_gate_kernel<<<nblocks, TPB, 0, stream>>>(x, log_sigma_raw, log_w_raw, ema_prob, out, nrows);
}